// Round 1
// baseline (124.465 us; speedup 1.0000x reference)
//
#include <hip/hip_runtime.h>

#define NB   8
#define S_   1024
#define DIN  1280
#define RANK 64
#define DOUT 1280
#define DOWN (RANK * DIN)          // 81920 floats
#define EMB  (DOWN + DOUT * RANK)  // 163840 floats per batch
#define XSTRIDE 1288               // x LDS row stride (bf16): 2576B, 16B-aligned, +4 banks/row

typedef __bf16 bf16x8 __attribute__((ext_vector_type(8)));
typedef __bf16 bf16x4 __attribute__((ext_vector_type(4)));
typedef float  f32x4  __attribute__((ext_vector_type(4)));

// Convert 8 fp32 -> bf16x8 (RNE casts; compiler emits v_cvt_pk_bf16_f32 pairs)
__device__ __forceinline__ bf16x8 cvt8(float4 f0, float4 f1) {
    bf16x8 v;
    v[0]=(__bf16)f0.x; v[1]=(__bf16)f0.y; v[2]=(__bf16)f0.z; v[3]=(__bf16)f0.w;
    v[4]=(__bf16)f1.x; v[5]=(__bf16)f1.y; v[6]=(__bf16)f1.z; v[7]=(__bf16)f1.w;
    return v;
}

// ---------------- single fused kernel: NO workspace, NO cvt prepass ----------------
// One WG = (batch b, 16 rows of S). Weights read as fp32 straight from embed
// (L2-hot: 1.3 MB/batch, batch pinned per XCD) and converted to bf16 fragments
// in registers at point of use. Eliminates d_ws entirely (and with it, the
// 256 MiB per-iteration workspace poison fill, if that fill is use-conditional).
__global__ __launch_bounds__(512, 2) void lora_fused(const float* __restrict__ x,
                                                     const float* __restrict__ embed,
                                                     float* __restrict__ out) {
    __shared__ __bf16 xls[16 * XSTRIDE];   // 41.2 KB bf16 x tile
    __shared__ float  pbuf[4][16][20];     // 5.1 KB  kh-reduce
    __shared__ __bf16 hld[16][80];         // 2.6 KB  h tile

    const int b    = blockIdx.x & 7;           // batch pinned per XCD
    const int s0   = (blockIdx.x >> 3) * 16;
    const int t    = threadIdx.x;
    const int w    = t >> 6;
    const int l    = t & 63;
    const int quad = l >> 4;
    const int lc   = l & 15;
    const int dq   = quad * 8;

    // ---- stage x tile: 16 rows x 1280 fp32, fully coalesced, cvt to bf16 ----
    {
        const int row = t >> 5;                // 0..15 (32 threads per row)
        const int c   = t & 31;                // float4 index within row chunk
        const float4* src = reinterpret_cast<const float4*>(x + (size_t)(b * S_ + s0 + row) * DIN);
        __bf16* drow = xls + row * XSTRIDE;
#pragma unroll
        for (int j = 0; j < 10; ++j) {
            float4 f = src[c + 32 * j];
            bf16x4 v;
            v[0]=(__bf16)f.x; v[1]=(__bf16)f.y; v[2]=(__bf16)f.z; v[3]=(__bf16)f.w;
            *reinterpret_cast<bf16x4*>(drow + c * 4 + 128 * j) = v;
        }
    }
    __syncthreads();

    // ---- phase 1: h = x @ w_down^T ----
    const int nt = w & 3;                      // n-tile (16 of 64 ranks)
    const int kh = w >> 2;                     // K half (640 each)
    const float*  wdrow  = embed + (size_t)b * EMB + (size_t)(nt * 16 + lc) * DIN + kh * 640;
    const __bf16* xlsrow = xls + lc * XSTRIDE + kh * 640;

    f32x4 acc = {0,0,0,0};
#pragma unroll 5
    for (int ks = 0; ks < 20; ++ks) {
        const int k = ks * 32 + dq;
        bf16x8 af = *reinterpret_cast<const bf16x8*>(xlsrow + k);      // ds_read_b128
        const float4* wp = reinterpret_cast<const float4*>(wdrow + k); // 2x16B fp32, L2-hot
        bf16x8 bf = cvt8(wp[0], wp[1]);
        acc = __builtin_amdgcn_mfma_f32_16x16x32_bf16(af, bf, acc, 0, 0, 0);
    }

    if (kh == 1) {
#pragma unroll
        for (int i = 0; i < 4; ++i) pbuf[nt][quad * 4 + i][lc] = acc[i];
    }
    __syncthreads();
    if (kh == 0) {
#pragma unroll
        for (int i = 0; i < 4; ++i) {
            float v = acc[i] + pbuf[nt][quad * 4 + i][lc];
            hld[quad * 4 + i][nt * 16 + lc] = (__bf16)v;
        }
    }
    __syncthreads();

    // ---- phase 2: out = h @ w_up^T (n-split 8) ----
    bf16x8 ha0 = *reinterpret_cast<const bf16x8*>(&hld[lc][dq]);
    bf16x8 ha1 = *reinterpret_cast<const bf16x8*>(&hld[lc][32 + dq]);
    const float* wu    = embed + (size_t)b * EMB + DOWN;
    float*       obase = out + (size_t)(b * S_ + s0 + quad * 4) * DOUT;

#pragma unroll 2
    for (int tt = 0; tt < 10; ++tt) {
        const int n = w + 8 * tt;
        const int o = n * 16 + lc;
        const float4* wr = reinterpret_cast<const float4*>(wu + (size_t)o * RANK);
        const int q2 = quad * 2;                       // float4 index of dq
        bf16x8 b0 = cvt8(wr[q2],     wr[q2 + 1]);      // floats [dq, dq+8)
        bf16x8 b1 = cvt8(wr[8 + q2], wr[9 + q2]);      // floats [32+dq, 32+dq+8)
        f32x4 c = {0,0,0,0};
        c = __builtin_amdgcn_mfma_f32_16x16x32_bf16(ha0, b0, c, 0, 0, 0);
        c = __builtin_amdgcn_mfma_f32_16x16x32_bf16(ha1, b1, c, 0, 0, 0);
#pragma unroll
        for (int i = 0; i < 4; ++i)
            obase[(size_t)i * DOUT + o] = c[i];
    }
}

extern "C" void kernel_launch(void* const* d_in, const int* in_sizes, int n_in,
                              void* d_out, int out_size, void* d_ws, size_t ws_size,
                              hipStream_t stream) {
    const float* x     = (const float*)d_in[0];
    const float* embed = (const float*)d_in[1];
    float*       out   = (float*)d_out;
    (void)in_sizes; (void)n_in; (void)out_size; (void)d_ws; (void)ws_size;

    lora_fused<<<dim3(512), dim3(512), 0, stream>>>(x, embed, out);
}

// Round 2
// 124.050 us; speedup vs baseline: 1.0033x; 1.0033x over previous
//
#include <hip/hip_runtime.h>

#define NB   8
#define S_   1024
#define DIN  1280
#define RANK 64
#define DOUT 1280
#define DOWN (RANK * DIN)          // 81920 floats
#define EMB  (DOWN + DOUT * RANK)  // 163840 floats per batch
#define XSTRIDE 1288               // x LDS row stride (bf16): 2576B, 16B-aligned, +4 banks/row

typedef __bf16 bf16x8 __attribute__((ext_vector_type(8)));
typedef __bf16 bf16x4 __attribute__((ext_vector_type(4)));
typedef float  f32x4  __attribute__((ext_vector_type(4)));

// Convert 8 fp32 -> bf16x8 (RNE casts; compiler emits v_cvt_pk_bf16_f32 pairs)
__device__ __forceinline__ bf16x8 cvt8(float4 f0, float4 f1) {
    bf16x8 v;
    v[0]=(__bf16)f0.x; v[1]=(__bf16)f0.y; v[2]=(__bf16)f0.z; v[3]=(__bf16)f0.w;
    v[4]=(__bf16)f1.x; v[5]=(__bf16)f1.y; v[6]=(__bf16)f1.z; v[7]=(__bf16)f1.w;
    return v;
}

// Fused LoRA, latency-optimized: deep explicit prefetch pipelines.
// Phase-1 weights double-buffered in registers (10 float4 per buffer, group 0
// issued before the staging barrier). Phase-2 tt=0 weights issued before the
// reduce barriers; rolling 1-deep prefetch through the tt loop.
__global__ __launch_bounds__(512, 2) void lora_fused(const float* __restrict__ x,
                                                     const float* __restrict__ embed,
                                                     float* __restrict__ out) {
    __shared__ __bf16 xls[16 * XSTRIDE];   // 41.2 KB bf16 x tile
    __shared__ float  pbuf[4][16][20];     // 5.1 KB  kh-reduce
    __shared__ __bf16 hld[16][80];         // 2.6 KB  h tile

    const int b    = blockIdx.x & 7;           // batch pinned per XCD
    const int s0   = (blockIdx.x >> 3) * 16;
    const int t    = threadIdx.x;
    const int w    = t >> 6;
    const int l    = t & 63;
    const int quad = l >> 4;
    const int lc   = l & 15;
    const int dq   = quad * 8;
    const int q2   = quad * 2;                 // float4 index of dq

    const int nt = w & 3;                      // n-tile (16 of 64 ranks)
    const int kh = w >> 2;                     // K half (640 each)
    const float4* wq =
        reinterpret_cast<const float4*>(embed + (size_t)b * EMB + (size_t)(nt * 16 + lc) * DIN + kh * 640);

    // ---- stage x tile: issue all 10 loads, then weight group 0, then cvt+store ----
    {
        const int row = t >> 5;                // 0..15 (32 threads per row)
        const int c   = t & 31;                // float4 index within row chunk
        const float4* src = reinterpret_cast<const float4*>(x + (size_t)(b * S_ + s0 + row) * DIN);
        float4 f[10];
#pragma unroll
        for (int j = 0; j < 10; ++j) f[j] = src[c + 32 * j];   // all 10 in flight

        // phase-1 weight group 0 (ks 0..4): in flight through staging + barrier
        float4 wA[10], wB[10];
#pragma unroll
        for (int j = 0; j < 5; ++j) { wA[2*j] = wq[j*8 + q2]; wA[2*j+1] = wq[j*8 + q2 + 1]; }

        __bf16* drow = xls + row * XSTRIDE;
#pragma unroll
        for (int j = 0; j < 10; ++j) {
            bf16x4 v;
            v[0]=(__bf16)f[j].x; v[1]=(__bf16)f[j].y; v[2]=(__bf16)f[j].z; v[3]=(__bf16)f[j].w;
            *reinterpret_cast<bf16x4*>(drow + c * 4 + 128 * j) = v;
        }
        __syncthreads();

        // ---- phase 1: h = x @ w_down^T, double-buffered weight groups ----
        const __bf16* xlsrow = xls + lc * XSTRIDE + kh * 640;
        f32x4 acc = {0,0,0,0};
#pragma unroll
        for (int g = 0; g < 4; ++g) {
            float4* cur = (g & 1) ? wB : wA;   // g is compile-time (full unroll) -> static
            float4* nxt = (g & 1) ? wA : wB;
            if (g < 3) {
#pragma unroll
                for (int j = 0; j < 5; ++j) {
                    nxt[2*j]   = wq[(g+1)*40 + j*8 + q2];
                    nxt[2*j+1] = wq[(g+1)*40 + j*8 + q2 + 1];
                }
            }
#pragma unroll
            for (int j = 0; j < 5; ++j) {
                const int ks = g * 5 + j;
                bf16x8 af = *reinterpret_cast<const bf16x8*>(xlsrow + ks * 32 + dq); // ds_read_b128
                acc = __builtin_amdgcn_mfma_f32_16x16x32_bf16(af, cvt8(cur[2*j], cur[2*j+1]), acc, 0, 0, 0);
            }
        }

        // ---- phase-2 tt=0 weight prefetch: in flight across both reduce barriers ----
        const float* wu = embed + (size_t)b * EMB + DOWN;
        const float4* wr0 = reinterpret_cast<const float4*>(wu + (size_t)(w * 16 + lc) * RANK);
        float4 u0 = wr0[q2], u1 = wr0[q2 + 1], u2 = wr0[8 + q2], u3 = wr0[9 + q2];

        // ---- kh reduce -> h tile (bf16) ----
        if (kh == 1) {
#pragma unroll
            for (int i = 0; i < 4; ++i) pbuf[nt][quad * 4 + i][lc] = acc[i];
        }
        __syncthreads();
        if (kh == 0) {
#pragma unroll
            for (int i = 0; i < 4; ++i) {
                float v = acc[i] + pbuf[nt][quad * 4 + i][lc];
                hld[quad * 4 + i][nt * 16 + lc] = (__bf16)v;
            }
        }
        __syncthreads();

        // ---- phase 2: out = h @ w_up^T (n-split 8), rolling prefetch ----
        bf16x8 ha0 = *reinterpret_cast<const bf16x8*>(&hld[lc][dq]);
        bf16x8 ha1 = *reinterpret_cast<const bf16x8*>(&hld[lc][32 + dq]);
        float* obase = out + (size_t)(b * S_ + s0 + quad * 4) * DOUT;

#pragma unroll
        for (int tt = 0; tt < 10; ++tt) {
            float4 n0, n1, n2, n3;
            if (tt < 9) {
                const float4* wrn =
                    reinterpret_cast<const float4*>(wu + (size_t)((w + 8 * (tt + 1)) * 16 + lc) * RANK);
                n0 = wrn[q2]; n1 = wrn[q2 + 1]; n2 = wrn[8 + q2]; n3 = wrn[9 + q2];
            }
            bf16x8 b0 = cvt8(u0, u1);
            bf16x8 b1 = cvt8(u2, u3);
            f32x4 c = {0,0,0,0};
            c = __builtin_amdgcn_mfma_f32_16x16x32_bf16(ha0, b0, c, 0, 0, 0);
            c = __builtin_amdgcn_mfma_f32_16x16x32_bf16(ha1, b1, c, 0, 0, 0);
            const int o = (w + 8 * tt) * 16 + lc;
#pragma unroll
            for (int i = 0; i < 4; ++i)
                obase[(size_t)i * DOUT + o] = c[i];
            u0 = n0; u1 = n1; u2 = n2; u3 = n3;
        }
    }
}

extern "C" void kernel_launch(void* const* d_in, const int* in_sizes, int n_in,
                              void* d_out, int out_size, void* d_ws, size_t ws_size,
                              hipStream_t stream) {
    const float* x     = (const float*)d_in[0];
    const float* embed = (const float*)d_in[1];
    float*       out   = (float*)d_out;
    (void)in_sizes; (void)n_in; (void)out_size; (void)d_ws; (void)ws_size;

    lora_fused<<<dim3(512), dim3(512), 0, stream>>>(x, embed, out);
}

// Round 3
// 100.315 us; speedup vs baseline: 1.2407x; 1.2366x over previous
//
#include <hip/hip_runtime.h>

#define NB   8
#define S_   1024
#define DIN  1280
#define RANK 64
#define DOUT 1280
#define DOWN (RANK * DIN)          // 81920
#define EMB  (DOWN + DOUT * RANK)  // 163840
#define XSTRIDE 1288               // x LDS row stride (bf16): 2576B, rows step 4 banks

// LDS layout (bytes), total 80896 -> 2 WG/CU (161792 <= 160 KiB with 2x81920 granularity)
#define XLS_OFF   0
#define XLS_BYTES (16 * XSTRIDE * 2)          // 41216
#define WB_OFF    XLS_BYTES                   // 41216 (16B aligned)
#define WB_BYTES  (2 * 16384)                 // 32768: double-buffered 16KB weight chunks
#define PB_OFF    (WB_OFF + WB_BYTES)         // 73984
#define PB_BYTES  (4 * 16 * 17 * 4)           // 4352
#define HL_OFF    (PB_OFF + PB_BYTES)         // 78336
#define HL_BYTES  (16 * 80 * 2)               // 2560
#define LDS_TOTAL (HL_OFF + HL_BYTES)         // 80896

typedef __bf16 bf16x8 __attribute__((ext_vector_type(8)));
typedef __bf16 bf16x4 __attribute__((ext_vector_type(4)));
typedef float  f32x4  __attribute__((ext_vector_type(4)));

// coalesced async global->LDS, 16B/lane; LDS dest = uniform base + lane*16
#define GLOAD16(gsrc, ldsoff)                                              \
    __builtin_amdgcn_global_load_lds(                                      \
        (const __attribute__((address_space(1))) void*)(gsrc),             \
        (__attribute__((address_space(3))) void*)(smem + (ldsoff)),        \
        16, 0, 0)

// ---------------- prep: embed fp32 -> bf16 (into d_ws) ----------------
__global__ __launch_bounds__(256) void cvt_embed(const float* __restrict__ src,
                                                 __bf16* __restrict__ dst, int n8) {
    const int i = blockIdx.x * 256 + threadIdx.x;
    if (i < n8) {
        const float4* s = reinterpret_cast<const float4*>(src) + (size_t)i * 2;
        float4 f0 = s[0], f1 = s[1];
        bf16x8 v;
        v[0]=(__bf16)f0.x; v[1]=(__bf16)f0.y; v[2]=(__bf16)f0.z; v[3]=(__bf16)f0.w;
        v[4]=(__bf16)f1.x; v[5]=(__bf16)f1.y; v[6]=(__bf16)f1.z; v[7]=(__bf16)f1.w;
        *reinterpret_cast<bf16x8*>(dst + (size_t)i * 8) = v;
    }
}

// ---------------- main: all weight fragments via LDS (coalesced stage) ----------------
// Phase-1 chunks: [2 kh][64 ranks][64 k] bf16 = 16KB, double-buffered, XOR-swizzled
// (byte ^= (row&7)<<4) via pre-swizzled global source + swizzled ds_read.
// Phase-2 chunks: [128 out-rows][64 k] bf16 = 16KB, same treatment; tt=0 staged
// during phase-1's last iteration (reduce barriers hide its latency).
__global__ __launch_bounds__(512, 2) void lora_main(const float* __restrict__ x,
                                                    const __bf16* __restrict__ ew,
                                                    float* __restrict__ out) {
    extern __shared__ char smem[];
    __bf16* xls = (__bf16*)(smem + XLS_OFF);
    float (*pbuf)[16][17] = (float(*)[16][17])(smem + PB_OFF);
    __bf16 (*hld)[80]     = (__bf16(*)[80])(smem + HL_OFF);

    const int b    = blockIdx.x & 7;           // batch pinned per XCD
    const int s0   = (blockIdx.x >> 3) * 16;
    const int t    = threadIdx.x;
    const int w    = t >> 6;
    const int l    = t & 63;
    const int quad = l >> 4;
    const int lc   = l & 15;
    const int dq   = quad * 8;

    const int nt = w & 3;                      // n-tile (16 of 64 ranks)
    const int kh = w >> 2;                     // K half (640 each)

    // ---- per-lane pre-swizzled stage sources (rule #21: linear dest, swz source) ----
    const char* wdB = (const char*)(ew + (size_t)b * EMB);
    const char* wuB = wdB + (size_t)DOWN * 2;
    const int d0 = w * 2048 + l * 16;          // this lane's dest byte in a 16KB chunk
    const int d1 = d0 + 1024;
    // phase 1 decode: d -> [kh][r(64)][colB(128)]
    const int kh0 = d0 >> 13,        kh1 = d1 >> 13;
    const int r0  = (d0 >> 7) & 63,  r1  = (d1 >> 7) & 63;
    const int cB0 = d0 & 127,        cB1 = d1 & 127;
    const char* p1a = wdB + r0 * 2560 + kh0 * 1280 + (cB0 ^ ((r0 & 7) << 4));
    const char* p1b = wdB + r1 * 2560 + kh1 * 1280 + (cB1 ^ ((r1 & 7) << 4));
    // phase 2 decode: d -> [r(128)][colB(128)]; rows contiguous (128B each)
    const char* p2a = wuB + (d0 ^ (((d0 >> 7) & 7) << 4));
    const char* p2b = wuB + (d1 ^ (((d1 >> 7) & 7) << 4));
    const int ldsA = WB_OFF + w * 2048;        // wave-uniform LDS dest (buf 0)
    const int bswz = (lc & 7) << 4;            // read-side swizzle

    // ---- prologue: issue w chunk 0 (in flight under x staging), stage x tile ----
    GLOAD16(p1a, ldsA);
    GLOAD16(p1b, ldsA + 1024);
    {
        const int row = t >> 5;                // 0..15 (32 threads per row)
        const int c   = t & 31;
        const float4* src = reinterpret_cast<const float4*>(x + (size_t)(b * S_ + s0 + row) * DIN);
        __bf16* drow = xls + row * XSTRIDE;
#pragma unroll
        for (int j = 0; j < 10; ++j) {
            float4 f = src[c + 32 * j];
            bf16x4 v;
            v[0]=(__bf16)f.x; v[1]=(__bf16)f.y; v[2]=(__bf16)f.z; v[3]=(__bf16)f.w;
            *reinterpret_cast<bf16x4*>(drow + c * 4 + 128 * j) = v;
        }
    }
    __syncthreads();                           // drains vmcnt: chunk 0 + x ready

    // ---- phase 1: h = x @ w_down^T, LDS-staged weights, 2-phase pipeline ----
    const __bf16* xrow = xls + lc * XSTRIDE + kh * 640;
    const int brow = kh * 8192 + (nt * 16 + lc) * 128;   // byte offset in chunk
    f32x4 acc = {0,0,0,0};
#pragma unroll
    for (int c = 0; c < 10; ++c) {
        const int nb = (c & 1) ^ 1;
        if (c < 9) {                           // stage next chunk into other buffer
            GLOAD16(p1a + (c + 1) * 128, nb * 16384 + ldsA);
            GLOAD16(p1b + (c + 1) * 128, nb * 16384 + ldsA + 1024);
        } else {                               // stage phase-2 tt=0 (nb==0 -> buf0)
            GLOAD16(p2a, ldsA);
            GLOAD16(p2b, ldsA + 1024);
        }
        const char* bb = smem + WB_OFF + (c & 1) * 16384;
#pragma unroll
        for (int j = 0; j < 2; ++j) {
            bf16x8 af = *reinterpret_cast<const bf16x8*>(xrow + c * 64 + j * 32 + dq);
            bf16x8 bf = *reinterpret_cast<const bf16x8*>(bb + ((brow + j * 64 + quad * 16) ^ bswz));
            acc = __builtin_amdgcn_mfma_f32_16x16x32_bf16(af, bf, acc, 0, 0, 0);
        }
        __syncthreads();                       // next chunk staged + buffers safe
    }

    // ---- kh reduce -> h tile (bf16); barriers also cover tt=0 stage ----
    if (kh == 1) {
#pragma unroll
        for (int i = 0; i < 4; ++i) pbuf[nt][quad * 4 + i][lc] = acc[i];
    }
    __syncthreads();
    if (kh == 0) {
#pragma unroll
        for (int i = 0; i < 4; ++i) {
            float v = acc[i] + pbuf[nt][quad * 4 + i][lc];
            hld[quad * 4 + i][nt * 16 + lc] = (__bf16)v;
        }
    }
    __syncthreads();

    // ---- phase 2: out = h @ w_up^T, LDS-staged weights ----
    bf16x8 ha0 = *reinterpret_cast<const bf16x8*>(&hld[lc][dq]);
    bf16x8 ha1 = *reinterpret_cast<const bf16x8*>(&hld[lc][32 + dq]);
    float* obase = out + (size_t)(b * S_ + s0 + quad * 4) * DOUT;
    const int prow = (w * 16 + lc) * 128;      // byte offset in chunk

#pragma unroll
    for (int tt = 0; tt < 10; ++tt) {
        if (tt < 9) {
            const int nb = (tt & 1) ^ 1;
            GLOAD16(p2a + (tt + 1) * 16384, nb * 16384 + ldsA);
            GLOAD16(p2b + (tt + 1) * 16384, nb * 16384 + ldsA + 1024);
        }
        const char* bb = smem + WB_OFF + (tt & 1) * 16384;
        bf16x8 b0 = *reinterpret_cast<const bf16x8*>(bb + ((prow + quad * 16) ^ bswz));
        bf16x8 b1 = *reinterpret_cast<const bf16x8*>(bb + ((prow + 64 + quad * 16) ^ bswz));
        f32x4 c4 = {0,0,0,0};
        c4 = __builtin_amdgcn_mfma_f32_16x16x32_bf16(ha0, b0, c4, 0, 0, 0);
        c4 = __builtin_amdgcn_mfma_f32_16x16x32_bf16(ha1, b1, c4, 0, 0, 0);
        const int o = (w + 8 * tt) * 16 + lc;
#pragma unroll
        for (int i = 0; i < 4; ++i)
            obase[(size_t)i * DOUT + o] = c4[i];
        if (tt < 9) __syncthreads();
    }
}

extern "C" void kernel_launch(void* const* d_in, const int* in_sizes, int n_in,
                              void* d_out, int out_size, void* d_ws, size_t ws_size,
                              hipStream_t stream) {
    const float* x     = (const float*)d_in[0];
    const float* embed = (const float*)d_in[1];
    float*       out   = (float*)d_out;
    __bf16*      ew    = (__bf16*)d_ws;        // 8 x 163840 bf16 = 2.6 MB
    (void)in_sizes; (void)n_in; (void)out_size; (void)ws_size;

    cvt_embed<<<dim3(640), dim3(256), 0, stream>>>(embed, ew, NB * EMB / 8);
    lora_main<<<dim3(512), dim3(512), LDS_TOTAL, stream>>>(x, ew, out);
}